// Round 3
// baseline (45.033 us; speedup 1.0000x reference)
//
#include <hip/hip_runtime.h>

// LRT loss: ce  = -(log_softmax(outputs) * targets).sum()/B
//           lrt = -((A[index] @ soft_labels[index]) * log_softmax(outputs)).sum()/B
// out = ce + (epoch >= 10 ? lrt : 0)
// B=8192, C=64, A is [N,64,64] f32. Memory-bound: 134 MB gathered A rows.
//
// One wave = one sample. Coalesced A reads: chunk k, lane l loads float4 at
// flat idx k*64+l -> each instruction reads a contiguous 1 KB block.
// Lane owns elements [k*256+4l .. +3] = row (k*4 + l>>4), cols 4*(l&15)..+3.
// sum_r v_r*ls_r == sum_lanes p_lane * ls[row(lane)] -> no group reduction.
// Single kernel: block partial -> one atomicAdd (d_out zeroed via memsetAsync).

#define CDIM 64

__global__ __launch_bounds__(256, 4) void lrt_fused(
    const float* __restrict__ outputs,
    const float* __restrict__ targets,
    const float* __restrict__ A,
    const float* __restrict__ soft_labels,
    const int* __restrict__ epoch,
    const int* __restrict__ index,
    float* __restrict__ out,
    int B)
{
    const int w = threadIdx.x >> 6;   // wave in block (0..3)
    const int l = threadIdx.x & 63;   // lane
    const int b = blockIdx.x * 4 + w; // sample

    float val = 0.0f;
    if (b < B) {                       // wave-uniform
        const int idx = index[b];
        const float gate = (epoch[0] >= 10) ? 1.0f : 0.0f;

        // Issue all 16 coalesced 1KB loads up front (independent of everything below)
        const float4* __restrict__ A4 =
            reinterpret_cast<const float4*>(A + (size_t)idx * (CDIM * CDIM));
        float4 a0, a1, a2, a3, a4, a5, a6, a7, a8, a9, a10, a11, a12, a13, a14, a15;
        a0  = A4[ 0 * 64 + l];  a1  = A4[ 1 * 64 + l];
        a2  = A4[ 2 * 64 + l];  a3  = A4[ 3 * 64 + l];
        a4  = A4[ 4 * 64 + l];  a5  = A4[ 5 * 64 + l];
        a6  = A4[ 6 * 64 + l];  a7  = A4[ 7 * 64 + l];
        a8  = A4[ 8 * 64 + l];  a9  = A4[ 9 * 64 + l];
        a10 = A4[10 * 64 + l];  a11 = A4[11 * 64 + l];
        a12 = A4[12 * 64 + l];  a13 = A4[13 * 64 + l];
        a14 = A4[14 * 64 + l];  a15 = A4[15 * 64 + l];

        const float x  = outputs[(size_t)b * CDIM + l];
        const float tg = targets[(size_t)b * CDIM + l];
        const float sv = soft_labels[(size_t)idx * CDIM + l];

        // wave softmax (lane = class) — runs while A loads are in flight
        float m = x;
        #pragma unroll
        for (int o = 32; o >= 1; o >>= 1) m = fmaxf(m, __shfl_xor(m, o));
        float e = expf(x - m);
        float s = e;
        #pragma unroll
        for (int o = 32; o >= 1; o >>= 1) s += __shfl_xor(s, o);
        const float ls = x - m - logf(s);   // log_softmax[b][l]

        // broadcast the 4 soft-label values this lane needs (constant over chunks)
        const int c0 = (l & 15) * 4;
        const float sb0 = __shfl(sv, c0 + 0);
        const float sb1 = __shfl(sv, c0 + 1);
        const float sb2 = __shfl(sv, c0 + 2);
        const float sb3 = __shfl(sv, c0 + 3);
        const int rbase = l >> 4;           // row offset within each chunk's 4 rows

        float acc = 0.0f;
        #define CONSUME(k, av)                                            \
        {                                                                 \
            float p = av.x * sb0;                                         \
            p = fmaf(av.y, sb1, p);                                       \
            p = fmaf(av.z, sb2, p);                                       \
            p = fmaf(av.w, sb3, p);                                       \
            acc = fmaf(p, __shfl(ls, k * 4 + rbase), acc);                \
        }
        CONSUME(0, a0)   CONSUME(1, a1)   CONSUME(2, a2)   CONSUME(3, a3)
        CONSUME(4, a4)   CONSUME(5, a5)   CONSUME(6, a6)   CONSUME(7, a7)
        CONSUME(8, a8)   CONSUME(9, a9)   CONSUME(10, a10) CONSUME(11, a11)
        CONSUME(12, a12) CONSUME(13, a13) CONSUME(14, a14) CONSUME(15, a15)
        #undef CONSUME

        val = -ls * tg - gate * acc;
    }

    // wave reduce
    #pragma unroll
    for (int o = 32; o >= 1; o >>= 1) val += __shfl_xor(val, o);

    __shared__ float red[4];
    if (l == 0) red[w] = val;
    __syncthreads();
    if (threadIdx.x == 0) {
        const float inv_b = 1.0f / (float)B;
        atomicAdd(out, (red[0] + red[1] + red[2] + red[3]) * inv_b);
    }
}

extern "C" void kernel_launch(void* const* d_in, const int* in_sizes, int n_in,
                              void* d_out, int out_size, void* d_ws, size_t ws_size,
                              hipStream_t stream) {
    const float* outputs     = (const float*)d_in[0];
    const float* targets     = (const float*)d_in[1];
    const float* A           = (const float*)d_in[2];
    const float* soft_labels = (const float*)d_in[3];
    const int*   epoch       = (const int*)d_in[4];
    const int*   index       = (const int*)d_in[5];

    const int B = in_sizes[5];              // 8192 samples
    const int nblocks = (B + 3) / 4;        // one wave per sample

    hipMemsetAsync(d_out, 0, sizeof(float), stream);
    lrt_fused<<<nblocks, 256, 0, stream>>>(outputs, targets, A, soft_labels,
                                           epoch, index, (float*)d_out, B);
}

// Round 4
// 29.706 us; speedup vs baseline: 1.5159x; 1.5159x over previous
//
#include <hip/hip_runtime.h>

// LRT loss: ce  = -(log_softmax(outputs) * targets).sum()/B
//           lrt = -((A[index] @ soft_labels[index]) * log_softmax(outputs)).sum()/B
// out = ce + (epoch >= 10 ? lrt : 0)
// B=8192, C=64, A is [N,64,64] f32. Memory-bound: 134 MB gathered A rows.
//
// One wave = one sample. Coalesced A reads: chunk k, lane l loads float4 at
// flat idx k*64+l -> each instruction reads a contiguous 1 KB block.
// Lane owns row (k*4 + l>>4), cols 4*(l&15)..+3 of chunk k.
// sum_r v_r*ls_r == sum_lanes p_lane * ls[row(lane)] -> no group reduction.
// idx scalarized via readfirstlane -> A loads use SGPR base + imm offsets.
// Two-stage reduction (NO same-address atomics — R3 showed they cost ~11us).

#define CDIM 64

__global__ __launch_bounds__(256, 4) void lrt_stage1(
    const float* __restrict__ outputs,
    const float* __restrict__ targets,
    const float* __restrict__ A,
    const float* __restrict__ soft_labels,
    const int* __restrict__ epoch,
    const int* __restrict__ index,
    float* __restrict__ partial,
    int B)
{
    const int w = threadIdx.x >> 6;   // wave in block (0..3)
    const int l = threadIdx.x & 63;   // lane
    const int b = blockIdx.x * 4 + w; // sample

    float val = 0.0f;
    if (b < B) {                       // wave-uniform
        // idx is wave-uniform: force it scalar so A-loads get an SGPR base
        const int idx = __builtin_amdgcn_readfirstlane(index[b]);
        const float gate = (epoch[0] >= 10) ? 1.0f : 0.0f;

        // Issue all 16 coalesced 1KB loads up front
        const float4* __restrict__ A4 =
            reinterpret_cast<const float4*>(A + (size_t)idx * (CDIM * CDIM));
        float4 a0, a1, a2, a3, a4, a5, a6, a7, a8, a9, a10, a11, a12, a13, a14, a15;
        a0  = A4[ 0 * 64 + l];  a1  = A4[ 1 * 64 + l];
        a2  = A4[ 2 * 64 + l];  a3  = A4[ 3 * 64 + l];
        a4  = A4[ 4 * 64 + l];  a5  = A4[ 5 * 64 + l];
        a6  = A4[ 6 * 64 + l];  a7  = A4[ 7 * 64 + l];
        a8  = A4[ 8 * 64 + l];  a9  = A4[ 9 * 64 + l];
        a10 = A4[10 * 64 + l];  a11 = A4[11 * 64 + l];
        a12 = A4[12 * 64 + l];  a13 = A4[13 * 64 + l];
        a14 = A4[14 * 64 + l];  a15 = A4[15 * 64 + l];

        const float x  = outputs[(size_t)b * CDIM + l];
        const float tg = targets[(size_t)b * CDIM + l];
        const float sv = soft_labels[(size_t)idx * CDIM + l];

        // wave softmax (lane = class) — overlaps with A loads in flight
        float m = x;
        #pragma unroll
        for (int o = 32; o >= 1; o >>= 1) m = fmaxf(m, __shfl_xor(m, o));
        float e = expf(x - m);
        float s = e;
        #pragma unroll
        for (int o = 32; o >= 1; o >>= 1) s += __shfl_xor(s, o);
        const float ls = x - m - logf(s);   // log_softmax[b][l]

        // broadcast the 4 soft-label values this lane needs (constant over chunks)
        const int c0 = (l & 15) * 4;
        const float sb0 = __shfl(sv, c0 + 0);
        const float sb1 = __shfl(sv, c0 + 1);
        const float sb2 = __shfl(sv, c0 + 2);
        const float sb3 = __shfl(sv, c0 + 3);
        const int rbase = l >> 4;           // row offset within each chunk's 4 rows

        float acc = 0.0f;
        #define CONSUME(k, av)                                            \
        {                                                                 \
            float p = av.x * sb0;                                         \
            p = fmaf(av.y, sb1, p);                                       \
            p = fmaf(av.z, sb2, p);                                       \
            p = fmaf(av.w, sb3, p);                                       \
            acc = fmaf(p, __shfl(ls, k * 4 + rbase), acc);                \
        }
        CONSUME(0, a0)   CONSUME(1, a1)   CONSUME(2, a2)   CONSUME(3, a3)
        CONSUME(4, a4)   CONSUME(5, a5)   CONSUME(6, a6)   CONSUME(7, a7)
        CONSUME(8, a8)   CONSUME(9, a9)   CONSUME(10, a10) CONSUME(11, a11)
        CONSUME(12, a12) CONSUME(13, a13) CONSUME(14, a14) CONSUME(15, a15)
        #undef CONSUME

        val = -ls * tg - gate * acc;
    }

    // wave reduce
    #pragma unroll
    for (int o = 32; o >= 1; o >>= 1) val += __shfl_xor(val, o);

    __shared__ float red[4];
    if (l == 0) red[w] = val;
    __syncthreads();
    if (threadIdx.x == 0)
        partial[blockIdx.x] = red[0] + red[1] + red[2] + red[3];
}

__global__ __launch_bounds__(256) void lrt_stage2(
    const float* __restrict__ partial, float* __restrict__ out, int n, int B)
{
    const int t = threadIdx.x;
    double acc = 0.0;
    for (int i = t; i < n; i += 256) acc += (double)partial[i];
    #pragma unroll
    for (int o = 32; o >= 1; o >>= 1) acc += __shfl_xor(acc, o);
    __shared__ double red[4];
    if ((t & 63) == 0) red[t >> 6] = acc;
    __syncthreads();
    if (t == 0) out[0] = (float)((red[0] + red[1] + red[2] + red[3]) / (double)B);
}

extern "C" void kernel_launch(void* const* d_in, const int* in_sizes, int n_in,
                              void* d_out, int out_size, void* d_ws, size_t ws_size,
                              hipStream_t stream) {
    const float* outputs     = (const float*)d_in[0];
    const float* targets     = (const float*)d_in[1];
    const float* A           = (const float*)d_in[2];
    const float* soft_labels = (const float*)d_in[3];
    const int*   epoch       = (const int*)d_in[4];
    const int*   index       = (const int*)d_in[5];

    const int B = in_sizes[5];              // 8192 samples
    const int nblocks = (B + 3) / 4;        // one wave per sample
    float* partial = (float*)d_ws;          // nblocks floats, overwritten each call

    lrt_stage1<<<nblocks, 256, 0, stream>>>(outputs, targets, A, soft_labels,
                                            epoch, index, partial, B);
    lrt_stage2<<<1, 256, 0, stream>>>(partial, (float*)d_out, nblocks, B);
}

// Round 5
// 28.952 us; speedup vs baseline: 1.5554x; 1.0261x over previous
//
#include <hip/hip_runtime.h>

// LRT loss: ce  = -(log_softmax(outputs) * targets).sum()/B
//           lrt = -((A[index] @ soft_labels[index]) * log_softmax(outputs)).sum()/B
// out = ce + (epoch >= 10 ? lrt : 0)
// B=8192, C=64, A is [N,64,64] f32. Memory-bound: 134 MB gathered A rows.
//
// One wave = one sample per iteration; waves grid-stride over samples so
// blocks are LONG-LIVED (R4 post-mortem: 0.6us blocks forced ~1.7 blocks/ns
// CP re-dispatch — above CP rate, CUs idled). Grid = 1024 blocks = 4/CU,
// all co-resident; each of the 4096 waves handles 2 samples.
// Coalesced A reads: chunk k, lane l loads float4 at flat idx k*64+l ->
// each instruction reads a contiguous 1 KB block.
// sum_r v_r*ls_r == sum_lanes p_lane * ls[row(lane)] -> no group reduction.

#define CDIM 64
#define NBLOCKS 1024

__global__ __launch_bounds__(256, 4) void lrt_stage1(
    const float* __restrict__ outputs,
    const float* __restrict__ targets,
    const float* __restrict__ A,
    const float* __restrict__ soft_labels,
    const int* __restrict__ epoch,
    const int* __restrict__ index,
    float* __restrict__ partial,
    int B)
{
    const int w = threadIdx.x >> 6;   // wave in block (0..3)
    const int l = threadIdx.x & 63;   // lane
    const int wave0 = blockIdx.x * 4 + w;
    const int nwaves = gridDim.x * 4;
    const float gate = (epoch[0] >= 10) ? 1.0f : 0.0f;

    float val = 0.0f;   // accumulates over all samples this wave handles

    for (int b = wave0; b < B; b += nwaves) {
        // idx is wave-uniform: force scalar so A-loads get an SGPR base
        const int idx = __builtin_amdgcn_readfirstlane(index[b]);

        // Issue all 16 coalesced 1KB loads up front
        const float4* __restrict__ A4 =
            reinterpret_cast<const float4*>(A + (size_t)idx * (CDIM * CDIM));
        float4 a0, a1, a2, a3, a4, a5, a6, a7, a8, a9, a10, a11, a12, a13, a14, a15;
        a0  = A4[ 0 * 64 + l];  a1  = A4[ 1 * 64 + l];
        a2  = A4[ 2 * 64 + l];  a3  = A4[ 3 * 64 + l];
        a4  = A4[ 4 * 64 + l];  a5  = A4[ 5 * 64 + l];
        a6  = A4[ 6 * 64 + l];  a7  = A4[ 7 * 64 + l];
        a8  = A4[ 8 * 64 + l];  a9  = A4[ 9 * 64 + l];
        a10 = A4[10 * 64 + l];  a11 = A4[11 * 64 + l];
        a12 = A4[12 * 64 + l];  a13 = A4[13 * 64 + l];
        a14 = A4[14 * 64 + l];  a15 = A4[15 * 64 + l];

        const float x  = outputs[(size_t)b * CDIM + l];
        const float tg = targets[(size_t)b * CDIM + l];
        const float sv = soft_labels[(size_t)idx * CDIM + l];

        // wave softmax (lane = class) — overlaps with A loads in flight
        float m = x;
        #pragma unroll
        for (int o = 32; o >= 1; o >>= 1) m = fmaxf(m, __shfl_xor(m, o));
        float e = expf(x - m);
        float s = e;
        #pragma unroll
        for (int o = 32; o >= 1; o >>= 1) s += __shfl_xor(s, o);
        const float ls = x - m - logf(s);   // log_softmax[b][l]

        // broadcast the 4 soft-label values this lane needs
        const int c0 = (l & 15) * 4;
        const float sb0 = __shfl(sv, c0 + 0);
        const float sb1 = __shfl(sv, c0 + 1);
        const float sb2 = __shfl(sv, c0 + 2);
        const float sb3 = __shfl(sv, c0 + 3);
        const int rbase = l >> 4;           // row offset within chunk's 4 rows

        float acc = 0.0f;
        #define CONSUME(k, av)                                            \
        {                                                                 \
            float p = av.x * sb0;                                         \
            p = fmaf(av.y, sb1, p);                                       \
            p = fmaf(av.z, sb2, p);                                       \
            p = fmaf(av.w, sb3, p);                                       \
            acc = fmaf(p, __shfl(ls, k * 4 + rbase), acc);                \
        }
        CONSUME(0, a0)   CONSUME(1, a1)   CONSUME(2, a2)   CONSUME(3, a3)
        CONSUME(4, a4)   CONSUME(5, a5)   CONSUME(6, a6)   CONSUME(7, a7)
        CONSUME(8, a8)   CONSUME(9, a9)   CONSUME(10, a10) CONSUME(11, a11)
        CONSUME(12, a12) CONSUME(13, a13) CONSUME(14, a14) CONSUME(15, a15)
        #undef CONSUME

        val += -ls * tg - gate * acc;
    }

    // wave reduce
    #pragma unroll
    for (int o = 32; o >= 1; o >>= 1) val += __shfl_xor(val, o);

    __shared__ float red[4];
    if (l == 0) red[w] = val;
    __syncthreads();
    if (threadIdx.x == 0)
        partial[blockIdx.x] = red[0] + red[1] + red[2] + red[3];
}

__global__ __launch_bounds__(256) void lrt_stage2(
    const float* __restrict__ partial, float* __restrict__ out, int n, int B)
{
    const int t = threadIdx.x;
    double acc = 0.0;
    for (int i = t; i < n; i += 256) acc += (double)partial[i];
    #pragma unroll
    for (int o = 32; o >= 1; o >>= 1) acc += __shfl_xor(acc, o);
    __shared__ double red[4];
    if ((t & 63) == 0) red[t >> 6] = acc;
    __syncthreads();
    if (t == 0) out[0] = (float)((red[0] + red[1] + red[2] + red[3]) / (double)B);
}

extern "C" void kernel_launch(void* const* d_in, const int* in_sizes, int n_in,
                              void* d_out, int out_size, void* d_ws, size_t ws_size,
                              hipStream_t stream) {
    const float* outputs     = (const float*)d_in[0];
    const float* targets     = (const float*)d_in[1];
    const float* A           = (const float*)d_in[2];
    const float* soft_labels = (const float*)d_in[3];
    const int*   epoch       = (const int*)d_in[4];
    const int*   index       = (const int*)d_in[5];

    const int B = in_sizes[5];          // 8192 samples
    float* partial = (float*)d_ws;      // NBLOCKS floats, overwritten each call

    lrt_stage1<<<NBLOCKS, 256, 0, stream>>>(outputs, targets, A, soft_labels,
                                            epoch, index, partial, B);
    lrt_stage2<<<1, 256, 0, stream>>>(partial, (float*)d_out, NBLOCKS, B);
}